// Round 2
// baseline (53020.569 us; speedup 1.0000x reference)
//
#include <hip/hip_runtime.h>
#include <cstdint>

// ---------------------------------------------------------------------------
// 3-layer LSTM (B=32, T=1024, H=I=512), PyTorch gate order (i,f,g,o).
//  - x_proj GEMMs: split-bf16 MFMA (A regions [hi|hi|lo], B regions [hi|lo|hi]
//    over K'=1536) -> ~1.6e-5 relative accuracy at bf16 MFMA rate.
//  - Recurrence: fp32 VALU, 256 WGs (= #CUs, 1/CU via 84KB LDS) =
//    4 batch-groups x 64 unit-groups; W_hh slice in LDS; h exchanged via
//    global bf16 hi/lo (doubles as next layer's GEMM input); 64-WG
//    monotonic-counter barrier per batch-group (plain launch, guarded spin).
//  - Time chunked CT=256: G buffer 64MiB reused; c persisted in global.
//  - Total workspace ~140 MiB. No cooperative launch, no capture-illegal API.
// ---------------------------------------------------------------------------

typedef unsigned short u16;
typedef short short8 __attribute__((ext_vector_type(8)));     // bf16x8 MFMA frag
typedef unsigned short ushort8 __attribute__((ext_vector_type(8)));
typedef float f32x4 __attribute__((ext_vector_type(4)));

#define NB 32
#define NT 1024
#define NH 512
#define N4H 2048
#define KS 1024   // stored row: [hi(512) | lo(512)] bf16
#define CT 256    // time chunk
#define MROWS (NB * NT)

__device__ __forceinline__ u16 f2bf(float f) {
  uint32_t u = __float_as_uint(f);
  uint32_t r = (u + 0x7fffu + ((u >> 16) & 1u)) >> 16;
  return (u16)r;
}
__device__ __forceinline__ float bf2f(u16 h) {
  return __uint_as_float((uint32_t)h << 16);
}

__device__ __forceinline__ void gload_lds16(const void* g, void* l) {
  __builtin_amdgcn_global_load_lds(
      (const __attribute__((address_space(1))) unsigned int*)g,
      (__attribute__((address_space(3))) unsigned int*)l, 16, 0, 0);
}

// X [32,4,1024,128] f32 -> st[n=b*1024+t][hi(512)|lo(512)] bf16
__global__ void k_gather_x(const float* __restrict__ X, u16* __restrict__ st) {
  int64_t i = (int64_t)blockIdx.x * 256 + threadIdx.x;  // 16,777,216
  int k = (int)(i & 511);
  int t = (int)((i >> 9) & 1023);
  int b = (int)(i >> 19);
  int c = k >> 7, f = k & 127;
  float v = X[(((int64_t)(b * 4 + c) * 1024 + t) << 7) + f];
  u16 hi = f2bf(v);
  u16 lo = f2bf(v - bf2f(hi));
  int64_t n = (int64_t)b * 1024 + t;
  st[n * KS + k] = hi;
  st[n * KS + 512 + k] = lo;
}

// W [2048,512] f32 -> Wp[2048][hi(512)|lo(512)] bf16
__global__ void k_split_w(const float* __restrict__ W, u16* __restrict__ Wp) {
  int i = blockIdx.x * 256 + threadIdx.x;  // 1,048,576
  int r = i >> 9, k = i & 511;
  float v = W[i];
  u16 hi = f2bf(v);
  u16 lo = f2bf(v - bf2f(hi));
  Wp[r * KS + k] = hi;
  Wp[r * KS + 512 + k] = lo;
}

__global__ void k_bias(const float* __restrict__ bi, const float* __restrict__ bh,
                       float* __restrict__ bo) {
  int i = blockIdx.x * 256 + threadIdx.x;
  if (i < N4H) bo[i] = bi[i] + bh[i];
}

// G[b*CT+dt][2048] = st[b*1024+t0+dt][:] * Wp^T + bias   (split-bf16, K'=1536)
// 128x128 tile, BK=64, 4 waves 2x2, global_load_lds staging (m97 structure).
__launch_bounds__(256, 2)
__global__ void k_xproj(const u16* __restrict__ A, const u16* __restrict__ Wp,
                        const float* __restrict__ bias, float* __restrict__ G,
                        int t0) {
  __shared__ u16 As[128 * 64];
  __shared__ u16 Bs[128 * 64];
  const int tid = threadIdx.x;
  const int lane = tid & 63;
  const int wv = tid >> 6;
  const int wm = wv & 1, wn = wv >> 1;
  const int ntile = blockIdx.x & 15;
  const int mtile = blockIdx.x >> 4;          // 0..63
  const int b = mtile >> 1;
  const int dt0 = (mtile & 1) << 7;
  const int64_t arow0 = (int64_t)b * NT + t0 + dt0;   // global st row
  const int grow0 = mtile * 128;                      // G chunk row
  const int brow0 = ntile * 128;

  f32x4 acc[4][4];
#pragma unroll
  for (int m = 0; m < 4; ++m)
#pragma unroll
    for (int n = 0; n < 4; ++n) acc[m][n] = (f32x4){0.f, 0.f, 0.f, 0.f};

  const int srow = tid >> 3;       // 0..31
  const int scol = (tid & 7) * 8;  // elements; *2B = lane-linear 16B LDS dma

  for (int kt = 0; kt < 24; ++kt) {
    const int r = kt >> 3;
    const int abase = ((r == 2) ? 512 : 0) + ((kt & 7) << 6);  // A: hi,hi,lo
    const int bbase = ((r == 1) ? 512 : 0) + ((kt & 7) << 6);  // B: hi,lo,hi
#pragma unroll
    for (int i = 0; i < 4; ++i) {
      int row = srow + i * 32;
      int e = row * 64 + scol;
      gload_lds16(A + (arow0 + row) * KS + abase + scol, As + e);
      gload_lds16(Wp + (int64_t)(brow0 + row) * KS + bbase + scol, Bs + e);
    }
    __syncthreads();
#pragma unroll
    for (int kk = 0; kk < 2; ++kk) {
      const int krow = kk * 32 + (lane >> 4) * 8;
      short8 af[4], bf[4];
#pragma unroll
      for (int m = 0; m < 4; ++m)
        af[m] = *(const short8*)&As[(wm * 64 + m * 16 + (lane & 15)) * 64 + krow];
#pragma unroll
      for (int n = 0; n < 4; ++n)
        bf[n] = *(const short8*)&Bs[(wn * 64 + n * 16 + (lane & 15)) * 64 + krow];
#pragma unroll
      for (int m = 0; m < 4; ++m)
#pragma unroll
        for (int n = 0; n < 4; ++n)
          acc[m][n] = __builtin_amdgcn_mfma_f32_16x16x32_bf16(af[m], bf[n], acc[m][n], 0, 0, 0);
    }
    __syncthreads();
  }

  // C/D: col = lane&15, row = (lane>>4)*4 + j  [m89-verified]
  const int cb = lane & 15;
  const int rb = (lane >> 4) * 4;
#pragma unroll
  for (int m = 0; m < 4; ++m) {
#pragma unroll
    for (int n = 0; n < 4; ++n) {
      const int grow = grow0 + wm * 64 + m * 16 + rb;
      const int gcol = brow0 + wn * 64 + n * 16 + cb;
      const float bv = bias[gcol];
#pragma unroll
      for (int j = 0; j < 4; ++j)
        G[(int64_t)(grow + j) * N4H + gcol] = acc[m][n][j] + bv;
    }
  }
}

// Recurrent chunk: steps t0..t0+CT-1. 256 WGs x 256 thr, plain launch,
// 1 block/CU forced by 84KB LDS -> all co-resident.
// WG: bg=wg>>6 (8 batches), ug=wg&63 (8 units -> 32 gate rows).
// Dot thread: b_d=tid&7, u_d=(tid>>3)&7, g_d=tid>>6. State thread tid<64.
#define WPAD 516
__launch_bounds__(256, 1)
__global__ void k_lstm(const float* __restrict__ Whh, const float* __restrict__ G,
                       u16* __restrict__ st, float* __restrict__ cbuf,
                       unsigned* __restrict__ ctr, int t0) {
  __shared__ float Wl[32 * WPAD];
  __shared__ float hl[8 * WPAD];
  __shared__ float gl[256];
  const int tid = threadIdx.x;
  const int wg = blockIdx.x;
  const int bg = wg >> 6;
  const int ug = wg & 63;

  {  // stage 32 W_hh rows (once per launch)
    const int row_l = tid >> 3;
    const int ck = (tid & 7) * 64;
    const int gate = row_l >> 3, u_l = row_l & 7;
    const int grow = gate * 512 + ug * 8 + u_l;
    const float* src = Whh + (int64_t)grow * 512 + ck;
    float* dst = Wl + row_l * WPAD + ck;
#pragma unroll
    for (int i = 0; i < 64; i += 4) *(float4*)(dst + i) = *(const float4*)(src + i);
  }
  const int b_d = tid & 7, u_d = (tid >> 3) & 7, g_d = tid >> 6;
  const int row_d = g_d * 512 + ug * 8 + u_d;
  const float* wrow = Wl + (g_d * 8 + u_d) * WPAD;
  const float* hrow = hl + b_d * WPAD;
  const int b_s = bg * 8 + (tid & 7), u_s = ug * 8 + (tid >> 3);  // state-owner
  float cst = 0.f;
  if (t0 > 0 && tid < 64) cst = cbuf[b_s * NH + u_s];
  __syncthreads();

  for (int s = 0; s < CT; ++s) {
    const int ts = t0 + s;
    // stage h_prev (hi+lo) for our 8 batches
    if (ts == 0) {
      for (int i = tid; i < 8 * WPAD; i += 256) hl[i] = 0.f;
    } else {
      const int b_row = tid >> 5, c0 = (tid & 31) * 16;
      const u16* hp = st + ((int64_t)(bg * 8 + b_row) * NT + (ts - 1)) * KS;
      float* dst = hl + b_row * WPAD + c0;
      ushort8 ha = *(const ushort8*)(hp + c0);
      ushort8 la = *(const ushort8*)(hp + 512 + c0);
      ushort8 hb = *(const ushort8*)(hp + c0 + 8);
      ushort8 lb = *(const ushort8*)(hp + 512 + c0 + 8);
#pragma unroll
      for (int j = 0; j < 8; ++j) dst[j] = bf2f(ha[j]) + bf2f(la[j]);
#pragma unroll
      for (int j = 0; j < 8; ++j) dst[8 + j] = bf2f(hb[j]) + bf2f(lb[j]);
    }
    __syncthreads();

    float gacc = G[((int64_t)(bg * 8 + b_d) * CT + s) * N4H + row_d];

    float a0 = 0.f, a1 = 0.f, a2 = 0.f, a3 = 0.f;
#pragma unroll 8
    for (int k = 0; k < 512; k += 4) {
      float4 w = *(const float4*)(wrow + k);
      float4 h = *(const float4*)(hrow + k);
      a0 = fmaf(w.x, h.x, a0);
      a1 = fmaf(w.y, h.y, a1);
      a2 = fmaf(w.z, h.z, a2);
      a3 = fmaf(w.w, h.w, a3);
    }
    gl[tid] = (a0 + a1) + (a2 + a3) + gacc;
    __syncthreads();

    if (tid < 64) {
      float ig = gl[tid], fg = gl[64 + tid], gg = gl[128 + tid], og = gl[192 + tid];
      float i_s = 1.f / (1.f + expf(-ig));
      float f_s = 1.f / (1.f + expf(-fg));
      float g_t = tanhf(gg);
      float o_s = 1.f / (1.f + expf(-og));
      cst = f_s * cst + i_s * g_t;
      float h = o_s * tanhf(cst);
      u16* hp = st + ((int64_t)b_s * NT + ts) * KS;
      u16 hhi = f2bf(h);
      hp[u_s] = hhi;
      hp[512 + u_s] = f2bf(h - bf2f(hhi));
      __threadfence();  // flush h agent-wide before signaling
    }
    __syncthreads();

    // batch-group barrier: monotonic counter over 64 WGs (guarded spin)
    if (tid == 0) {
      __hip_atomic_fetch_add(&ctr[bg * 32], 1u, __ATOMIC_RELEASE, __HIP_MEMORY_SCOPE_AGENT);
      const unsigned tgt = (unsigned)(s + 1) * 64u;
      int guard = 0;
      while (__hip_atomic_load(&ctr[bg * 32], __ATOMIC_ACQUIRE, __HIP_MEMORY_SCOPE_AGENT) < tgt) {
        if (++guard > (1 << 20)) break;  // fail to wrong-output, never hang
      }
    }
    __syncthreads();
  }

  if (tid < 64) cbuf[b_s * NH + u_s] = cst;
}

// out[32,80] = (hi+lo of st[:,1023,:]) @ W_out^T + b_out
__global__ void k_final(const u16* __restrict__ st, const float* __restrict__ Wout,
                        const float* __restrict__ bout, float* __restrict__ out) {
  const int b = blockIdx.x;
  const int o = threadIdx.x;
  if (o >= 80) return;
  const u16* hp = st + ((int64_t)b * NT + (NT - 1)) * KS;
  float acc = bout[o];
  for (int k = 0; k < 512; ++k)
    acc += (bf2f(hp[k]) + bf2f(hp[512 + k])) * Wout[o * 512 + k];
  out[b * 80 + o] = acc;
}

extern "C" void kernel_launch(void* const* d_in, const int* in_sizes, int n_in,
                              void* d_out, int out_size, void* d_ws, size_t ws_size,
                              hipStream_t stream) {
  const float* X = (const float*)d_in[0];
  const float* Wih[3] = {(const float*)d_in[1], (const float*)d_in[5], (const float*)d_in[9]};
  const float* Whh[3] = {(const float*)d_in[2], (const float*)d_in[6], (const float*)d_in[10]};
  const float* bih[3] = {(const float*)d_in[3], (const float*)d_in[7], (const float*)d_in[11]};
  const float* bhh[3] = {(const float*)d_in[4], (const float*)d_in[8], (const float*)d_in[12]};
  const float* Wout = (const float*)d_in[13];
  const float* bout = (const float*)d_in[14];
  float* out = (float*)d_out;

  char* ws = (char*)d_ws;
  size_t off = 0;
  auto alloc = [&](size_t bytes) {
    char* p = ws + off;
    off = (off + bytes + 255) & ~(size_t)255;
    return p;
  };
  u16* st = (u16*)alloc((size_t)MROWS * KS * 2);          // 64 MiB
  float* G = (float*)alloc((size_t)NB * CT * N4H * 4);    // 64 MiB
  u16* Wp[3];
  for (int l = 0; l < 3; ++l) Wp[l] = (u16*)alloc((size_t)N4H * KS * 2);  // 4 MiB each
  float* bias[3];
  for (int l = 0; l < 3; ++l) bias[l] = (float*)alloc(N4H * 4);
  float* cbuf = (float*)alloc(NB * NH * 4);               // 64 KiB
  unsigned* ctr = (unsigned*)alloc(512);
  // total ~140.4 MiB

  k_gather_x<<<65536, 256, 0, stream>>>(X, st);
  for (int l = 0; l < 3; ++l) {
    k_split_w<<<4096, 256, 0, stream>>>(Wih[l], Wp[l]);
    k_bias<<<8, 256, 0, stream>>>(bih[l], bhh[l], bias[l]);
  }

  for (int l = 0; l < 3; ++l) {
    for (int c = 0; c < NT / CT; ++c) {
      const int t0 = c * CT;
      k_xproj<<<1024, 256, 0, stream>>>(st, Wp[l], bias[l], G, t0);
      hipMemsetAsync(ctr, 0, 512, stream);
      k_lstm<<<256, 256, 0, stream>>>(Whh[l], G, st, cbuf, ctr, t0);
    }
  }

  k_final<<<32, 128, 0, stream>>>(st, Wout, bout, out);
}

// Round 3
// 48645.413 us; speedup vs baseline: 1.0899x; 1.0899x over previous
//
#include <hip/hip_runtime.h>
#include <cstdint>

// ---------------------------------------------------------------------------
// 3-layer LSTM (B=32, T=1024, H=I=512), PyTorch gate order (i,f,g,o).
//  - x_proj GEMMs: split-bf16 MFMA (A regions [hi|hi|lo], B regions [hi|lo|hi]
//    over K'=1536) -> fp32-class accuracy at bf16 MFMA rate.
//  - Recurrence: MFMA with W_hh split-bf16 held entirely in REGISTERS.
//    64 WGs x 256 thr (4 waves = 2x2 tiles of M=32 gate-rows x N=32 batches).
//    Row permutation (unit,gate) makes all 4 gates of a (unit,batch) land in
//    one lane's f32x4 acc -> state update fully in-register, all 256 lanes.
//    h exchanged via global st as bf16 hi/lo (doubles as next layer's GEMM
//    input); 64-WG flag barrier (per-WG release store + __all poll), no RMW.
//  - Time chunked CT=256: G buffer 64MiB reused; c persisted in global.
// ---------------------------------------------------------------------------

typedef unsigned short u16;
typedef short short8 __attribute__((ext_vector_type(8)));
typedef unsigned short ushort8 __attribute__((ext_vector_type(8)));
typedef float f32x4 __attribute__((ext_vector_type(4)));

#define NB 32
#define NT 1024
#define NH 512
#define N4H 2048
#define KS 1024   // stored row: [hi(512) | lo(512)] bf16
#define CT 256    // time chunk
#define MROWS (NB * NT)

__device__ __forceinline__ u16 f2bf(float f) {
  uint32_t u = __float_as_uint(f);
  uint32_t r = (u + 0x7fffu + ((u >> 16) & 1u)) >> 16;
  return (u16)r;
}
__device__ __forceinline__ float bf2f(u16 h) {
  return __uint_as_float((uint32_t)h << 16);
}
__device__ __forceinline__ float sigm(float x) { return 1.f / (1.f + __expf(-x)); }
__device__ __forceinline__ float tanh_s(float x) {
  float a = fabsf(x);
  float e = __expf(-2.f * a);
  float t = (1.f - e) / (1.f + e);
  return copysignf(t, x);
}

__device__ __forceinline__ void gload_lds16(const void* g, void* l) {
  __builtin_amdgcn_global_load_lds(
      (const __attribute__((address_space(1))) unsigned int*)g,
      (__attribute__((address_space(3))) unsigned int*)l, 16, 0, 0);
}

// X [32,4,1024,128] f32 -> st[n=b*1024+t][hi(512)|lo(512)] bf16
__global__ void k_gather_x(const float* __restrict__ X, u16* __restrict__ st) {
  int64_t i = (int64_t)blockIdx.x * 256 + threadIdx.x;  // 16,777,216
  int k = (int)(i & 511);
  int t = (int)((i >> 9) & 1023);
  int b = (int)(i >> 19);
  int c = k >> 7, f = k & 127;
  float v = X[(((int64_t)(b * 4 + c) * 1024 + t) << 7) + f];
  u16 hi = f2bf(v);
  u16 lo = f2bf(v - bf2f(hi));
  int64_t n = (int64_t)b * 1024 + t;
  st[n * KS + k] = hi;
  st[n * KS + 512 + k] = lo;
}

// W [2048,512] f32 -> Wp[2048][hi(512)|lo(512)] bf16
__global__ void k_split_w(const float* __restrict__ W, u16* __restrict__ Wp) {
  int i = blockIdx.x * 256 + threadIdx.x;  // 1,048,576
  int r = i >> 9, k = i & 511;
  float v = W[i];
  u16 hi = f2bf(v);
  u16 lo = f2bf(v - bf2f(hi));
  Wp[r * KS + k] = hi;
  Wp[r * KS + 512 + k] = lo;
}

__global__ void k_bias(const float* __restrict__ bi, const float* __restrict__ bh,
                       float* __restrict__ bo) {
  int i = blockIdx.x * 256 + threadIdx.x;
  if (i < N4H) bo[i] = bi[i] + bh[i];
}

// G[b*CT+dt][2048] = st[b*1024+t0+dt][:] * Wp^T + bias   (split-bf16, K'=1536)
// 128x128 tile, BK=64, 4 waves 2x2, global_load_lds staging (m97 structure).
__launch_bounds__(256, 2)
__global__ void k_xproj(const u16* __restrict__ A, const u16* __restrict__ Wp,
                        const float* __restrict__ bias, float* __restrict__ G,
                        int t0) {
  __shared__ u16 As[128 * 64];
  __shared__ u16 Bs[128 * 64];
  const int tid = threadIdx.x;
  const int lane = tid & 63;
  const int wv = tid >> 6;
  const int wm = wv & 1, wn = wv >> 1;
  const int ntile = blockIdx.x & 15;
  const int mtile = blockIdx.x >> 4;          // 0..63
  const int b = mtile >> 1;
  const int dt0 = (mtile & 1) << 7;
  const int64_t arow0 = (int64_t)b * NT + t0 + dt0;   // global st row
  const int grow0 = mtile * 128;                      // G chunk row
  const int brow0 = ntile * 128;

  f32x4 acc[4][4];
#pragma unroll
  for (int m = 0; m < 4; ++m)
#pragma unroll
    for (int n = 0; n < 4; ++n) acc[m][n] = (f32x4){0.f, 0.f, 0.f, 0.f};

  const int srow = tid >> 3;       // 0..31
  const int scol = (tid & 7) * 8;  // elements; *2B = lane-linear 16B LDS dma

  for (int kt = 0; kt < 24; ++kt) {
    const int r = kt >> 3;
    const int abase = ((r == 2) ? 512 : 0) + ((kt & 7) << 6);  // A: hi,hi,lo
    const int bbase = ((r == 1) ? 512 : 0) + ((kt & 7) << 6);  // B: hi,lo,hi
#pragma unroll
    for (int i = 0; i < 4; ++i) {
      int row = srow + i * 32;
      int e = row * 64 + scol;
      gload_lds16(A + (arow0 + row) * KS + abase + scol, As + e);
      gload_lds16(Wp + (int64_t)(brow0 + row) * KS + bbase + scol, Bs + e);
    }
    __syncthreads();
#pragma unroll
    for (int kk = 0; kk < 2; ++kk) {
      const int krow = kk * 32 + (lane >> 4) * 8;
      short8 af[4], bf[4];
#pragma unroll
      for (int m = 0; m < 4; ++m)
        af[m] = *(const short8*)&As[(wm * 64 + m * 16 + (lane & 15)) * 64 + krow];
#pragma unroll
      for (int n = 0; n < 4; ++n)
        bf[n] = *(const short8*)&Bs[(wn * 64 + n * 16 + (lane & 15)) * 64 + krow];
#pragma unroll
      for (int m = 0; m < 4; ++m)
#pragma unroll
        for (int n = 0; n < 4; ++n)
          acc[m][n] = __builtin_amdgcn_mfma_f32_16x16x32_bf16(af[m], bf[n], acc[m][n], 0, 0, 0);
    }
    __syncthreads();
  }

  // C/D: col = lane&15, row = (lane>>4)*4 + j  [m89-verified]
  const int cb = lane & 15;
  const int rb = (lane >> 4) * 4;
#pragma unroll
  for (int m = 0; m < 4; ++m) {
#pragma unroll
    for (int n = 0; n < 4; ++n) {
      const int grow = grow0 + wm * 64 + m * 16 + rb;
      const int gcol = brow0 + wn * 64 + n * 16 + cb;
      const float bv = bias[gcol];
#pragma unroll
      for (int j = 0; j < 4; ++j)
        G[(int64_t)(grow + j) * N4H + gcol] = acc[m][n][j] + bv;
    }
  }
}

// ---------------------------------------------------------------------------
// Recurrent chunk, register-resident W_hh, MFMA, flag barrier.
// 64 WGs x 256 thr. WG ug owns units ug*8..ug*8+7 (x4 gates = 32 rows), all
// 32 batches. Wave wv: mt=wv&1 (unit-half), nt=wv>>1 (batch-half).
// A-tile row tr (0..15) <-> (unit_local = mt*4 + tr>>2, gate = tr&3), so
// lane's acc j-components = gates i,f,g,o of unit (mt*4 + lane>>4),
// batch (nt*16 + lane&15).  K' = 1536 regions: A=[Whi|Whi|Wlo], B=[hhi|hlo|hhi].
// ---------------------------------------------------------------------------
__launch_bounds__(256, 1)
__global__ void k_lstm(const float* __restrict__ Whh, const float* __restrict__ G,
                       u16* __restrict__ st, float* __restrict__ cbuf,
                       unsigned* __restrict__ flags, int t0, unsigned base) {
  const int tid = threadIdx.x;
  const int lane = tid & 63;
  const int wv = tid >> 6;
  const int mt = wv & 1, nt = wv >> 1;
  const int ug = blockIdx.x;      // 0..63
  const int q = lane >> 4;        // 0..3
  const int cb = lane & 15;

  // --- stage this lane's 32 W_hh frags (split bf16) into registers ---
  short8 whi[16], wlo[16];
  {
    const int tr = lane & 15;                 // A-row within tile
    const int gate = tr & 3;
    const int u_row = mt * 4 + (tr >> 2);
    const int64_t R = (int64_t)gate * 512 + ug * 8 + u_row;
    const float* wsrc = Whh + R * 512 + q * 8;
#pragma unroll
    for (int kk = 0; kk < 16; ++kk) {
      float4 a = *(const float4*)(wsrc + kk * 32);
      float4 b = *(const float4*)(wsrc + kk * 32 + 4);
      float v[8] = {a.x, a.y, a.z, a.w, b.x, b.y, b.z, b.w};
      ushort8 hi8, lo8;
#pragma unroll
      for (int e = 0; e < 8; ++e) {
        u16 h = f2bf(v[e]);
        hi8[e] = h;
        lo8[e] = f2bf(v[e] - bf2f(h));
      }
      whi[kk] = (short8)hi8;
      wlo[kk] = (short8)lo8;
    }
  }

  const int bat = nt * 16 + cb;
  const int ucol = ug * 8 + mt * 4 + q;
  float cst = (t0 > 0) ? cbuf[bat * NH + ucol] : 0.f;

  for (int s = 0; s < CT; ++s) {
    const int ts = t0 + s;

    // G loads: independent of the barrier, issue first
    const float* gp = G + ((int64_t)bat * CT + s) * N4H + ucol;
    float g0 = gp[0], g1 = gp[512], g2 = gp[1024], g3 = gp[1536];

    f32x4 acc0 = {0.f, 0.f, 0.f, 0.f};
    f32x4 acc1 = {0.f, 0.f, 0.f, 0.f};
    f32x4 acc2 = {0.f, 0.f, 0.f, 0.f};

    if (ts > 0) {
      if (s > 0) {  // wait for all 64 WGs to have published h(ts-1)
        const unsigned tgt = base + (unsigned)s;
        int gd = 0;
        for (;;) {
          unsigned f = __hip_atomic_load(&flags[lane], __ATOMIC_ACQUIRE,
                                         __HIP_MEMORY_SCOPE_AGENT);
          if (__all((int)(f >= tgt))) break;
          __builtin_amdgcn_s_sleep(1);
          if (++gd > (1 << 18)) return;  // co-residency broke: fail fast, no hang
        }
      }
      // h frags straight from global (immediate-offset dwordx4 loads)
      const u16* hb = st + ((int64_t)bat * NT + (ts - 1)) * KS + q * 8;
#pragma unroll
      for (int kk = 0; kk < 16; ++kk) {
        short8 hh = *(const short8*)(hb + kk * 32);        // hi plane
        short8 hl = *(const short8*)(hb + 512 + kk * 32);  // lo plane
        acc0 = __builtin_amdgcn_mfma_f32_16x16x32_bf16(whi[kk], hh, acc0, 0, 0, 0);
        acc1 = __builtin_amdgcn_mfma_f32_16x16x32_bf16(whi[kk], hl, acc1, 0, 0, 0);
        acc2 = __builtin_amdgcn_mfma_f32_16x16x32_bf16(wlo[kk], hh, acc2, 0, 0, 0);
      }
    }

    float ip = (acc0[0] + acc1[0] + acc2[0]) + g0;
    float fp = (acc0[1] + acc1[1] + acc2[1]) + g1;
    float gg = (acc0[2] + acc1[2] + acc2[2]) + g2;
    float op = (acc0[3] + acc1[3] + acc2[3]) + g3;
    float i_s = sigm(ip), f_s = sigm(fp), g_t = tanh_s(gg), o_s = sigm(op);
    cst = f_s * cst + i_s * g_t;
    float h = o_s * tanh_s(cst);

    u16 hhi = f2bf(h);
    u16 hlo = f2bf(h - bf2f(hhi));
    u16* hp = st + ((int64_t)bat * NT + ts) * KS + ucol;
    hp[0] = hhi;
    hp[512] = hlo;
    __threadfence();     // h agent-visible before signaling
    __syncthreads();     // all 4 waves' stores fenced
    if (tid == 0)
      __hip_atomic_store(&flags[ug], base + (unsigned)s + 1, __ATOMIC_RELEASE,
                         __HIP_MEMORY_SCOPE_AGENT);
  }

  cbuf[bat * NH + ucol] = cst;
}

// out[32,80] = (hi+lo of st[:,1023,:]) @ W_out^T + b_out
__global__ void k_final(const u16* __restrict__ st, const float* __restrict__ Wout,
                        const float* __restrict__ bout, float* __restrict__ out) {
  const int b = blockIdx.x;
  const int o = threadIdx.x;
  if (o >= 80) return;
  const u16* hp = st + ((int64_t)b * NT + (NT - 1)) * KS;
  float acc = bout[o];
  for (int k = 0; k < 512; ++k)
    acc += (bf2f(hp[k]) + bf2f(hp[512 + k])) * Wout[o * 512 + k];
  out[b * 80 + o] = acc;
}

extern "C" void kernel_launch(void* const* d_in, const int* in_sizes, int n_in,
                              void* d_out, int out_size, void* d_ws, size_t ws_size,
                              hipStream_t stream) {
  const float* X = (const float*)d_in[0];
  const float* Wih[3] = {(const float*)d_in[1], (const float*)d_in[5], (const float*)d_in[9]};
  const float* Whh[3] = {(const float*)d_in[2], (const float*)d_in[6], (const float*)d_in[10]};
  const float* bih[3] = {(const float*)d_in[3], (const float*)d_in[7], (const float*)d_in[11]};
  const float* bhh[3] = {(const float*)d_in[4], (const float*)d_in[8], (const float*)d_in[12]};
  const float* Wout = (const float*)d_in[13];
  const float* bout = (const float*)d_in[14];
  float* out = (float*)d_out;

  char* ws = (char*)d_ws;
  size_t off = 0;
  auto alloc = [&](size_t bytes) {
    char* p = ws + off;
    off = (off + bytes + 255) & ~(size_t)255;
    return p;
  };
  u16* st = (u16*)alloc((size_t)MROWS * KS * 2);          // 64 MiB
  float* G = (float*)alloc((size_t)NB * CT * N4H * 4);    // 64 MiB
  u16* Wp[3];
  for (int l = 0; l < 3; ++l) Wp[l] = (u16*)alloc((size_t)N4H * KS * 2);  // 4 MiB each
  float* bias[3];
  for (int l = 0; l < 3; ++l) bias[l] = (float*)alloc(N4H * 4);
  float* cbuf = (float*)alloc(NB * NH * 4);               // 64 KiB
  unsigned* flags = (unsigned*)alloc(64 * 4);
  // total ~140.4 MiB

  hipMemsetAsync(flags, 0, 64 * 4, stream);
  k_gather_x<<<65536, 256, 0, stream>>>(X, st);
  for (int l = 0; l < 3; ++l) {
    k_split_w<<<4096, 256, 0, stream>>>(Wih[l], Wp[l]);
    k_bias<<<8, 256, 0, stream>>>(bih[l], bhh[l], bias[l]);
  }

  for (int l = 0; l < 3; ++l) {
    for (int c = 0; c < NT / CT; ++c) {
      const int t0 = c * CT;
      const unsigned base = (unsigned)(l * 4 + c) * CT;
      k_xproj<<<1024, 256, 0, stream>>>(st, Wp[l], bias[l], G, t0);
      k_lstm<<<64, 256, 0, stream>>>(Whh[l], G, st, cbuf, flags, t0, base);
    }
  }

  k_final<<<32, 128, 0, stream>>>(st, Wout, bout, out);
}

// Round 4
// 22614.713 us; speedup vs baseline: 2.3445x; 2.1511x over previous
//
#include <hip/hip_runtime.h>
#include <cstdint>

// ---------------------------------------------------------------------------
// 3-layer LSTM (B=32, T=1024, H=I=512), PyTorch gate order (i,f,g,o).
//  - x_proj GEMMs: split-bf16 MFMA (A regions [hi|hi|lo], B regions [hi|lo|hi]
//    over K'=1536) -> fp32-class accuracy at bf16 MFMA rate.
//  - Recurrence: MFMA with W_hh split-bf16 in REGISTERS, 64 WGs x 256 thr.
//    Cross-WG h exchange via per-instruction-coherent (sc0 sc1) stores/loads
//    to the Infinity Cache -- NO threadfence (buffer_wbl2) and NO acquire
//    atomics (buffer_inv): round-3 profiling showed those cache-maintenance
//    ops cost ~15 us/step with all pipes idle.
//    Flag barrier: producer sc1-stores h, vmcnt(0), syncthreads, sc1 flag
//    store; consumers poll 64 flags with sc1 loads + __all.
//  - Time chunked CT=256: G buffer 64MiB reused; c persisted in global.
// ---------------------------------------------------------------------------

typedef unsigned short u16;
typedef short short8 __attribute__((ext_vector_type(8)));
typedef unsigned short ushort8 __attribute__((ext_vector_type(8)));
typedef float f32x4 __attribute__((ext_vector_type(4)));

#define NB 32
#define NT 1024
#define NH 512
#define N4H 2048
#define KS 1024   // stored row: [hi(512) | lo(512)] bf16
#define CT 256    // time chunk
#define MROWS (NB * NT)

__device__ __forceinline__ u16 f2bf(float f) {
  uint32_t u = __float_as_uint(f);
  uint32_t r = (u + 0x7fffu + ((u >> 16) & 1u)) >> 16;
  return (u16)r;
}
__device__ __forceinline__ float bf2f(u16 h) {
  return __uint_as_float((uint32_t)h << 16);
}
__device__ __forceinline__ float sigm(float x) { return 1.f / (1.f + __expf(-x)); }
__device__ __forceinline__ float tanh_s(float x) {
  float a = fabsf(x);
  float e = __expf(-2.f * a);
  float t = (1.f - e) / (1.f + e);
  return copysignf(t, x);
}

__device__ __forceinline__ void gload_lds16(const void* g, void* l) {
  __builtin_amdgcn_global_load_lds(
      (const __attribute__((address_space(1))) unsigned int*)g,
      (__attribute__((address_space(3))) unsigned int*)l, 16, 0, 0);
}

// --- per-instruction device-coherent (IC-level) accessors ---
__device__ __forceinline__ void ld16_sc(const u16* p, uint4& d) {
  asm volatile("global_load_dwordx4 %0, %1, off sc0 sc1" : "=v"(d) : "v"(p));
}
__device__ __forceinline__ unsigned ld_flag_sc(const unsigned* p) {
  unsigned r;
  asm volatile("global_load_dword %0, %1, off sc0 sc1\n\ts_waitcnt vmcnt(0)"
               : "=v"(r) : "v"(p) : "memory");
  return r;
}
__device__ __forceinline__ void st16b_sc(u16* p, unsigned v) {
  asm volatile("global_store_short %0, %1, off sc0 sc1" :: "v"(p), "v"(v) : "memory");
}
__device__ __forceinline__ void st32b_sc(unsigned* p, unsigned v) {
  asm volatile("global_store_dword %0, %1, off sc0 sc1" :: "v"(p), "v"(v) : "memory");
}

// X [32,4,1024,128] f32 -> st[n=b*1024+t][hi(512)|lo(512)] bf16
__global__ void k_gather_x(const float* __restrict__ X, u16* __restrict__ st) {
  int64_t i = (int64_t)blockIdx.x * 256 + threadIdx.x;  // 16,777,216
  int k = (int)(i & 511);
  int t = (int)((i >> 9) & 1023);
  int b = (int)(i >> 19);
  int c = k >> 7, f = k & 127;
  float v = X[(((int64_t)(b * 4 + c) * 1024 + t) << 7) + f];
  u16 hi = f2bf(v);
  u16 lo = f2bf(v - bf2f(hi));
  int64_t n = (int64_t)b * 1024 + t;
  st[n * KS + k] = hi;
  st[n * KS + 512 + k] = lo;
}

// W [2048,512] f32 -> Wp[2048][hi(512)|lo(512)] bf16
__global__ void k_split_w(const float* __restrict__ W, u16* __restrict__ Wp) {
  int i = blockIdx.x * 256 + threadIdx.x;  // 1,048,576
  int r = i >> 9, k = i & 511;
  float v = W[i];
  u16 hi = f2bf(v);
  u16 lo = f2bf(v - bf2f(hi));
  Wp[r * KS + k] = hi;
  Wp[r * KS + 512 + k] = lo;
}

__global__ void k_bias(const float* __restrict__ bi, const float* __restrict__ bh,
                       float* __restrict__ bo) {
  int i = blockIdx.x * 256 + threadIdx.x;
  if (i < N4H) bo[i] = bi[i] + bh[i];
}

// G[b*CT+dt][2048] = st[b*1024+t0+dt][:] * Wp^T + bias   (split-bf16, K'=1536)
// 128x128 tile, BK=64, 4 waves 2x2, global_load_lds staging (m97 structure).
__launch_bounds__(256, 2)
__global__ void k_xproj(const u16* __restrict__ A, const u16* __restrict__ Wp,
                        const float* __restrict__ bias, float* __restrict__ G,
                        int t0) {
  __shared__ u16 As[128 * 64];
  __shared__ u16 Bs[128 * 64];
  const int tid = threadIdx.x;
  const int lane = tid & 63;
  const int wv = tid >> 6;
  const int wm = wv & 1, wn = wv >> 1;
  const int ntile = blockIdx.x & 15;
  const int mtile = blockIdx.x >> 4;          // 0..63
  const int b = mtile >> 1;
  const int dt0 = (mtile & 1) << 7;
  const int64_t arow0 = (int64_t)b * NT + t0 + dt0;   // global st row
  const int grow0 = mtile * 128;                      // G chunk row
  const int brow0 = ntile * 128;

  f32x4 acc[4][4];
#pragma unroll
  for (int m = 0; m < 4; ++m)
#pragma unroll
    for (int n = 0; n < 4; ++n) acc[m][n] = (f32x4){0.f, 0.f, 0.f, 0.f};

  const int srow = tid >> 3;       // 0..31
  const int scol = (tid & 7) * 8;  // elements; *2B = lane-linear 16B LDS dma

  for (int kt = 0; kt < 24; ++kt) {
    const int r = kt >> 3;
    const int abase = ((r == 2) ? 512 : 0) + ((kt & 7) << 6);  // A: hi,hi,lo
    const int bbase = ((r == 1) ? 512 : 0) + ((kt & 7) << 6);  // B: hi,lo,hi
#pragma unroll
    for (int i = 0; i < 4; ++i) {
      int row = srow + i * 32;
      int e = row * 64 + scol;
      gload_lds16(A + (arow0 + row) * KS + abase + scol, As + e);
      gload_lds16(Wp + (int64_t)(brow0 + row) * KS + bbase + scol, Bs + e);
    }
    __syncthreads();
#pragma unroll
    for (int kk = 0; kk < 2; ++kk) {
      const int krow = kk * 32 + (lane >> 4) * 8;
      short8 af[4], bf[4];
#pragma unroll
      for (int m = 0; m < 4; ++m)
        af[m] = *(const short8*)&As[(wm * 64 + m * 16 + (lane & 15)) * 64 + krow];
#pragma unroll
      for (int n = 0; n < 4; ++n)
        bf[n] = *(const short8*)&Bs[(wn * 64 + n * 16 + (lane & 15)) * 64 + krow];
#pragma unroll
      for (int m = 0; m < 4; ++m)
#pragma unroll
        for (int n = 0; n < 4; ++n)
          acc[m][n] = __builtin_amdgcn_mfma_f32_16x16x32_bf16(af[m], bf[n], acc[m][n], 0, 0, 0);
    }
    __syncthreads();
  }

  // C/D: col = lane&15, row = (lane>>4)*4 + j  [m89-verified]
  const int cb = lane & 15;
  const int rb = (lane >> 4) * 4;
#pragma unroll
  for (int m = 0; m < 4; ++m) {
#pragma unroll
    for (int n = 0; n < 4; ++n) {
      const int grow = grow0 + wm * 64 + m * 16 + rb;
      const int gcol = brow0 + wn * 64 + n * 16 + cb;
      const float bv = bias[gcol];
#pragma unroll
      for (int j = 0; j < 4; ++j)
        G[(int64_t)(grow + j) * N4H + gcol] = acc[m][n][j] + bv;
    }
  }
}

// ---------------------------------------------------------------------------
// Recurrent chunk, register-resident W_hh, MFMA, sc1 flag barrier.
// 64 WGs x 256 thr. WG ug owns units ug*8..ug*8+7 (x4 gates = 32 rows), all
// 32 batches. Wave wv: mt=wv&1 (unit-half), nt=wv>>1 (batch-half).
// Lane's acc j-components = gates i,f,g,o of unit (ug*8 + mt*4 + lane>>4),
// batch (nt*16 + lane&15).  K'=1536 regions: A=[Whi|Whi|Wlo], B=[hhi|hlo|hhi].
// ---------------------------------------------------------------------------
__launch_bounds__(256, 1)
__global__ void k_lstm(const float* __restrict__ Whh, const float* __restrict__ G,
                       u16* __restrict__ st, float* __restrict__ cbuf,
                       unsigned* __restrict__ flags, int t0, unsigned base) {
  const int tid = threadIdx.x;
  const int lane = tid & 63;
  const int wv = tid >> 6;
  const int mt = wv & 1, nt = wv >> 1;
  const int ug = blockIdx.x;      // 0..63
  const int q = lane >> 4;        // 0..3
  const int cb = lane & 15;

  // --- stage this lane's 32 W_hh frags (split bf16) into registers ---
  short8 whi[16], wlo[16];
  {
    const int tr = lane & 15;                 // A-row within tile
    const int gate = tr & 3;
    const int u_row = mt * 4 + (tr >> 2);
    const int64_t R = (int64_t)gate * 512 + ug * 8 + u_row;
    const float* wsrc = Whh + R * 512 + q * 8;
#pragma unroll
    for (int kk = 0; kk < 16; ++kk) {
      float4 a = *(const float4*)(wsrc + kk * 32);
      float4 b = *(const float4*)(wsrc + kk * 32 + 4);
      float v[8] = {a.x, a.y, a.z, a.w, b.x, b.y, b.z, b.w};
      ushort8 hi8, lo8;
#pragma unroll
      for (int e = 0; e < 8; ++e) {
        u16 h = f2bf(v[e]);
        hi8[e] = h;
        lo8[e] = f2bf(v[e] - bf2f(h));
      }
      whi[kk] = (short8)hi8;
      wlo[kk] = (short8)lo8;
    }
  }

  const int bat = nt * 16 + cb;
  const int ucol = ug * 8 + mt * 4 + q;
  float cst = (t0 > 0) ? cbuf[bat * NH + ucol] : 0.f;

  for (int s = 0; s < CT; ++s) {
    const int ts = t0 + s;

    // G loads: plain cached reads, independent of the barrier -> issue first
    const float* gp = G + ((int64_t)bat * CT + s) * N4H + ucol;
    float g0 = gp[0], g1 = gp[512], g2 = gp[1024], g3 = gp[1536];

    f32x4 acc0 = {0.f, 0.f, 0.f, 0.f};
    f32x4 acc1 = {0.f, 0.f, 0.f, 0.f};
    f32x4 acc2 = {0.f, 0.f, 0.f, 0.f};

    if (ts > 0) {
      if (s > 0) {  // wait for all 64 WGs to have published h(ts-1)
        const unsigned tgt = base + (unsigned)s;
        int gd = 0;
        for (;;) {
          unsigned f = ld_flag_sc(flags + lane);
          if (__all((int)(f >= tgt))) break;
          __builtin_amdgcn_s_sleep(1);
          if (++gd > (1 << 20)) return;  // co-residency broke: fail fast
        }
      }
      // h frags: coherent (IC) loads, issued in batch, one counted wait
      const u16* hb = st + ((int64_t)bat * NT + (ts - 1)) * KS + q * 8;
      uint4 hh[16], hl[16];
#pragma unroll
      for (int kk = 0; kk < 16; ++kk) {
        ld16_sc(hb + kk * 32, hh[kk]);
        ld16_sc(hb + 512 + kk * 32, hl[kk]);
      }
      asm volatile("s_waitcnt vmcnt(0)" ::: "memory");
      __builtin_amdgcn_sched_barrier(0);  // rule #18: keep MFMA after the wait
#pragma unroll
      for (int kk = 0; kk < 16; ++kk) {
        short8 hhv = __builtin_bit_cast(short8, hh[kk]);
        short8 hlv = __builtin_bit_cast(short8, hl[kk]);
        acc0 = __builtin_amdgcn_mfma_f32_16x16x32_bf16(whi[kk], hhv, acc0, 0, 0, 0);
        acc1 = __builtin_amdgcn_mfma_f32_16x16x32_bf16(whi[kk], hlv, acc1, 0, 0, 0);
        acc2 = __builtin_amdgcn_mfma_f32_16x16x32_bf16(wlo[kk], hhv, acc2, 0, 0, 0);
      }
    }

    float ip = (acc0[0] + acc1[0] + acc2[0]) + g0;
    float fp = (acc0[1] + acc1[1] + acc2[1]) + g1;
    float gg = (acc0[2] + acc1[2] + acc2[2]) + g2;
    float op = (acc0[3] + acc1[3] + acc2[3]) + g3;
    float i_s = sigm(ip), f_s = sigm(fp), g_t = tanh_s(gg), o_s = sigm(op);
    cst = f_s * cst + i_s * g_t;
    float h = o_s * tanh_s(cst);

    u16 hhi = f2bf(h);
    u16 hlo = f2bf(h - bf2f(hhi));
    u16* hp = st + ((int64_t)bat * NT + ts) * KS + ucol;
    st16b_sc(hp, (unsigned)hhi);
    st16b_sc(hp + 512, (unsigned)hlo);
    asm volatile("s_waitcnt vmcnt(0)" ::: "memory");  // h device-visible
    __syncthreads();                                   // all 4 waves done
    if (tid == 0)
      st32b_sc(flags + ug, base + (unsigned)s + 1);
  }

  cbuf[bat * NH + ucol] = cst;
}

// out[32,80] = (hi+lo of st[:,1023,:]) @ W_out^T + b_out
__global__ void k_final(const u16* __restrict__ st, const float* __restrict__ Wout,
                        const float* __restrict__ bout, float* __restrict__ out) {
  const int b = blockIdx.x;
  const int o = threadIdx.x;
  if (o >= 80) return;
  const u16* hp = st + ((int64_t)b * NT + (NT - 1)) * KS;
  float acc = bout[o];
  for (int k = 0; k < 512; ++k)
    acc += (bf2f(hp[k]) + bf2f(hp[512 + k])) * Wout[o * 512 + k];
  out[b * 80 + o] = acc;
}

extern "C" void kernel_launch(void* const* d_in, const int* in_sizes, int n_in,
                              void* d_out, int out_size, void* d_ws, size_t ws_size,
                              hipStream_t stream) {
  const float* X = (const float*)d_in[0];
  const float* Wih[3] = {(const float*)d_in[1], (const float*)d_in[5], (const float*)d_in[9]};
  const float* Whh[3] = {(const float*)d_in[2], (const float*)d_in[6], (const float*)d_in[10]};
  const float* bih[3] = {(const float*)d_in[3], (const float*)d_in[7], (const float*)d_in[11]};
  const float* bhh[3] = {(const float*)d_in[4], (const float*)d_in[8], (const float*)d_in[12]};
  const float* Wout = (const float*)d_in[13];
  const float* bout = (const float*)d_in[14];
  float* out = (float*)d_out;

  char* ws = (char*)d_ws;
  size_t off = 0;
  auto alloc = [&](size_t bytes) {
    char* p = ws + off;
    off = (off + bytes + 255) & ~(size_t)255;
    return p;
  };
  u16* st = (u16*)alloc((size_t)MROWS * KS * 2);          // 64 MiB
  float* G = (float*)alloc((size_t)NB * CT * N4H * 4);    // 64 MiB
  u16* Wp[3];
  for (int l = 0; l < 3; ++l) Wp[l] = (u16*)alloc((size_t)N4H * KS * 2);  // 4 MiB each
  float* bias[3];
  for (int l = 0; l < 3; ++l) bias[l] = (float*)alloc(N4H * 4);
  float* cbuf = (float*)alloc(NB * NH * 4);               // 64 KiB
  unsigned* flags = (unsigned*)alloc(64 * 4);
  // total ~140.4 MiB

  hipMemsetAsync(flags, 0, 64 * 4, stream);
  k_gather_x<<<65536, 256, 0, stream>>>(X, st);
  for (int l = 0; l < 3; ++l) {
    k_split_w<<<4096, 256, 0, stream>>>(Wih[l], Wp[l]);
    k_bias<<<8, 256, 0, stream>>>(bih[l], bhh[l], bias[l]);
  }

  for (int l = 0; l < 3; ++l) {
    for (int c = 0; c < NT / CT; ++c) {
      const int t0 = c * CT;
      const unsigned base = (unsigned)(l * 4 + c) * CT;
      k_xproj<<<1024, 256, 0, stream>>>(st, Wp[l], bias[l], G, t0);
      k_lstm<<<64, 256, 0, stream>>>(Whh[l], G, st, cbuf, flags, t0, base);
    }
  }

  k_final<<<32, 128, 0, stream>>>(st, Wout, bout, out);
}